// Round 13
// baseline (470.172 us; speedup 1.0000x reference)
//
#include <hip/hip_runtime.h>
#include <cstdint>

typedef __bf16 bf16;
typedef __bf16 bf16x8 __attribute__((ext_vector_type(8)));
typedef __bf16 bf16x4 __attribute__((ext_vector_type(4)));
typedef float  f32x4  __attribute__((ext_vector_type(4)));

#define SEQ  2048
#define HID  4096
#define DH   128
#define NQH  32
#define NKVH 8
#define NTOT 6144            /* 4096 q + 1024 k + 1024 v */
#define RSCALE 0.08838834764831845f   /* 1/sqrt(128) */
#define SOFTCAP 30.0f
#define L2E 1.4426950408889634f

// async global->LDS, 16B per lane; LDS dest = wave-uniform base + lane*16
__device__ __forceinline__ void gl2lds16(const void* g, void* l) {
  __builtin_amdgcn_global_load_lds(
      (const __attribute__((address_space(1))) unsigned int*)g,
      (__attribute__((address_space(3))) unsigned int*)l, 16, 0, 0);
}

// ---------------------------------------------------------------------------
// fp32 -> bf16 conversion (single stream over [wq;wk;wv])
// ---------------------------------------------------------------------------
__global__ void cvt3_kernel(const float* __restrict__ a, const float* __restrict__ b,
                            const float* __restrict__ c, bf16* __restrict__ out,
                            int na4, int nb4, int nc4) {
  const int n = na4 + nb4 + nc4;
  const int stride = gridDim.x * blockDim.x;
  for (int i = blockIdx.x * blockDim.x + threadIdx.x; i < n; i += stride) {
    const float* src; int j;
    if (i < na4)            { src = a; j = i; }
    else if (i < na4 + nb4) { src = b; j = i - na4; }
    else                    { src = c; j = i - na4 - nb4; }
    const float4 v = ((const float4*)src)[j];
    bf16x4 o = { (bf16)v.x, (bf16)v.y, (bf16)v.z, (bf16)v.w };
    *(bf16x4*)(out + (size_t)i * 4) = o;
  }
}

__global__ void cvt_kernel(const float* __restrict__ in, bf16* __restrict__ out, int n4) {
  const int stride = gridDim.x * blockDim.x;
  for (int i = blockIdx.x * blockDim.x + threadIdx.x; i < n4; i += stride) {
    const float4 v = ((const float4*)in)[i];
    bf16x4 o = { (bf16)v.x, (bf16)v.y, (bf16)v.z, (bf16)v.w };
    *(bf16x4*)(out + (size_t)i * 4) = o;
  }
}

// ---------------------------------------------------------------------------
// pre-attention RMSNorm: (S,H) fp32 -> bf16
// ---------------------------------------------------------------------------
__global__ void rmsnorm_kernel(const float* __restrict__ x, const float* __restrict__ w,
                               bf16* __restrict__ out) {
  const int s = blockIdx.x;
  const float* xr = x + (size_t)s * HID;
  float4 v[4];
  float ss = 0.f;
#pragma unroll
  for (int j = 0; j < 4; ++j) {
    v[j] = ((const float4*)xr)[threadIdx.x + j * 256];
    ss += v[j].x * v[j].x + v[j].y * v[j].y + v[j].z * v[j].z + v[j].w * v[j].w;
  }
#pragma unroll
  for (int m = 1; m < 64; m <<= 1) ss += __shfl_xor(ss, m);
  __shared__ float red[4];
  if ((threadIdx.x & 63) == 0) red[threadIdx.x >> 6] = ss;
  __syncthreads();
  const float rn = rsqrtf((red[0] + red[1] + red[2] + red[3]) * (1.f / HID) + 1e-5f);
  bf16* orow = out + (size_t)s * HID;
#pragma unroll
  for (int j = 0; j < 4; ++j) {
    const int idx = (threadIdx.x + j * 256) * 4;
    const float4 wv = ((const float4*)w)[threadIdx.x + j * 256];
    bf16x4 o = { (bf16)(v[j].x * rn * wv.x), (bf16)(v[j].y * rn * wv.y),
                 (bf16)(v[j].z * rn * wv.z), (bf16)(v[j].w * rn * wv.w) };
    *(bf16x4*)(orow + idx) = o;
  }
}

// ---------------------------------------------------------------------------
// GEMM  C[M,N] = A[M,K] * B[N,K]^T   (R11-proven: 923 TF QKV at 3/CU)
// 128x128 tile, BK=64, 4 waves (2x2 of 64x64), 16x16x32 MFMA, 32 KB LDS.
// ---------------------------------------------------------------------------
template<bool FINAL>
__global__ __launch_bounds__(256, 3)
void gemm_bt(const bf16* __restrict__ A, const bf16* __restrict__ B,
             bf16* __restrict__ Cb, float* __restrict__ Cf,
             const float* __restrict__ resid, int M, int N, int K)
{
  __shared__ bf16 As[128 * 64];
  __shared__ bf16 Bs[128 * 64];
  const int tid  = threadIdx.x;
  const int lane = tid & 63;
  const int wave = tid >> 6;
  const int wm = wave >> 1, wn = wave & 1;

  // XCD-aware bijective swizzle (nwg % 8 == 0 for all our launches)
  const int gx = gridDim.x;
  const int nwg = gx * gridDim.y;
  int lin = blockIdx.x + gx * blockIdx.y;
  lin = (lin & 7) * (nwg >> 3) + (lin >> 3);
  const int m0 = (lin / gx) * 128, n0 = (lin % gx) * 128;

  f32x4 acc[4][4] = {};

  for (int kt = 0; kt < K; kt += 64) {
#pragma unroll
    for (int i = 0; i < 4; ++i) {
      const int c = wave * 4 + i;
      const int row = c * 8 + (lane >> 3);
      const int col8 = (lane & 7) ^ (row & 7);
      gl2lds16(A + (size_t)(m0 + row) * K + kt + col8 * 8, As + c * 512);
      gl2lds16(B + (size_t)(n0 + row) * K + kt + col8 * 8, Bs + c * 512);
    }
    __syncthreads();
#pragma unroll
    for (int ks = 0; ks < 2; ++ks) {
      bf16x8 af[4], bfv[4];
#pragma unroll
      for (int mi = 0; mi < 4; ++mi) {
        const int row = wm * 64 + mi * 16 + (lane & 15);
        const int slot = (ks * 4 + (lane >> 4)) ^ (row & 7);
        af[mi] = *(const bf16x8*)(As + row * 64 + slot * 8);
      }
#pragma unroll
      for (int ni = 0; ni < 4; ++ni) {
        const int row = wn * 64 + ni * 16 + (lane & 15);
        const int slot = (ks * 4 + (lane >> 4)) ^ (row & 7);
        bfv[ni] = *(const bf16x8*)(Bs + row * 64 + slot * 8);
      }
#pragma unroll
      for (int mi = 0; mi < 4; ++mi)
#pragma unroll
        for (int ni = 0; ni < 4; ++ni)
          acc[mi][ni] = __builtin_amdgcn_mfma_f32_16x16x32_bf16(af[mi], bfv[ni], acc[mi][ni], 0, 0, 0);
    }
    __syncthreads();
  }

#pragma unroll
  for (int mi = 0; mi < 4; ++mi) {
#pragma unroll
    for (int i = 0; i < 4; ++i) {
      const int m = m0 + wm * 64 + mi * 16 + (lane >> 4) * 4 + i;
#pragma unroll
      for (int ni = 0; ni < 4; ++ni) {
        const int n = n0 + wn * 64 + ni * 16 + (lane & 15);
        const float v = acc[mi][ni][i];
        if constexpr (FINAL) {
          Cf[(size_t)m * N + n] = v + resid[(size_t)m * N + n];
        } else {
          Cb[(size_t)m * N + n] = (bf16)v;
        }
      }
    }
  }
}

// ---------------------------------------------------------------------------
// QK RMSNorm + RoPE; one wave per (s, head). reads fused qkv proj (S x 6144).
// ---------------------------------------------------------------------------
__global__ void qkrope_kernel(const bf16* __restrict__ qkv,
                              const float* __restrict__ qw, const float* __restrict__ kw,
                              const float* __restrict__ cs, const float* __restrict__ sn,
                              bf16* __restrict__ qr, bf16* __restrict__ kr)
{
  const int w = blockIdx.x * 4 + (threadIdx.x >> 6);
  const int lane = threadIdx.x & 63;
  const int s = w / (NQH + NKVH);
  const int hh = w % (NQH + NKVH);
  const bf16* src; bf16* dst; const float* nw;
  if (hh < NQH) {
    src = qkv + (size_t)s * NTOT + hh * DH;
    dst = qr + ((size_t)hh * SEQ + s) * DH;
    nw = qw;
  } else {
    const int h2 = hh - NQH;
    src = qkv + (size_t)s * NTOT + 4096 + h2 * DH;
    dst = kr + ((size_t)h2 * SEQ + s) * DH;
    nw = kw;
  }
  const float x0 = (float)src[lane], x1 = (float)src[lane + 64];
  float ss = x0 * x0 + x1 * x1;
#pragma unroll
  for (int m = 1; m < 64; m <<= 1) ss += __shfl_xor(ss, m);
  const float rn = rsqrtf(ss * (1.f / DH) + 1e-5f);
  const float n0 = x0 * rn * nw[lane], n1 = x1 * rn * nw[lane + 64];
  const float c0 = cs[s * DH + lane],      s0 = sn[s * DH + lane];
  const float c1 = cs[s * DH + lane + 64], s1 = sn[s * DH + lane + 64];
  dst[lane]      = (bf16)(n0 * c0 - n1 * s0);
  dst[lane + 64] = (bf16)(n1 * c1 + n0 * s1);
}

// ---------------------------------------------------------------------------
// V transpose: fused qkv (S, 6144; v at col 5120+h*128) -> (NKV, D, S)
// ---------------------------------------------------------------------------
__global__ void vtrans_kernel(const bf16* __restrict__ qkv, bf16* __restrict__ vt)
{
  __shared__ bf16 tbuf[64][33];
  const int s0 = blockIdx.x * 64;
  const int d0 = blockIdx.y * 32;
  const int h  = blockIdx.z;
  const int tid = threadIdx.x;
  {
    const int col = tid & 31, r0 = tid >> 5;
    for (int r = r0; r < 64; r += 8)
      tbuf[r][col] = qkv[(size_t)(s0 + r) * NTOT + 5120 + h * DH + d0 + col];
  }
  __syncthreads();
  {
    const int sc = tid & 63, dr0 = tid >> 6;
    for (int d = dr0; d < 32; d += 4)
      vt[((size_t)h * DH + d0 + d) * SEQ + s0 + sc] = tbuf[sc][d];
  }
}

// ---------------------------------------------------------------------------
// Flash attention, causal + softcap, GQA. KVBLK=32, LDS 40 KB.
// R10-proven-correct geometry; launch_bounds(256,3) caps VGPR at 170 (kernel
// needs ~150 -> no spill, unlike R10's (256,4)=128 cap which spilled).
// Expected 3 blocks/CU = 12 waves/CU (vs 2 blocks/8 waves at KVBLK=64):
// finer tiles + more waves hide the per-tile latency chain and shrink the
// causal straggler tail.
// ---------------------------------------------------------------------------
__global__ __launch_bounds__(256, 3)
void attn_kernel(const bf16* __restrict__ Q, const bf16* __restrict__ Kr,
                 const bf16* __restrict__ Vt, bf16* __restrict__ Oa)
{
  __shared__ bf16 Ks[2][32 * 128];  // [kv][d], 16-slot swizzle
  __shared__ bf16 Vs[2][128 * 32];  // [d][kv], 4-slot swizzle
  __shared__ bf16 Ps[4][32 * 32];   // per-wave P, 4-slot swizzle

  const int tid = threadIdx.x, lane = tid & 63, wave = tid >> 6;
  const int rl = lane & 15, hi = lane >> 4;

  // balanced (bx, head) remap
  const int lin  = blockIdx.x + 16 * blockIdx.y;
  const int slot = lin >> 8, idx = lin & 255;
  const int bx   = slot ? (15 - (idx & 15)) : (idx & 15);
  const int head = (slot << 4) | (idx >> 4);
  const int kvh  = head >> 2;
  const int q0   = bx * 128;
  const int wq0  = q0 + wave * 32;

  const bf16* Qh = Q  + (size_t)head * SEQ * DH;
  const bf16* Kh = Kr + (size_t)kvh * SEQ * DH;
  const bf16* Vh = Vt + (size_t)kvh * DH * SEQ;

  bf16x8 qf[2][4];
#pragma unroll
  for (int mt = 0; mt < 2; ++mt)
#pragma unroll
    for (int kc = 0; kc < 4; ++kc) {
      const int r = wq0 + mt * 16 + rl;
      qf[mt][kc] = *(const bf16x8*)(Qh + (size_t)r * DH + kc * 32 + hi * 8);
    }

  float lsum[2][4] = {};
  f32x4 o_acc[2][8] = {};

  const int ntiles = q0 / 32 + 4;   // covers kv up to q0+127

  auto stage = [&](int t, int b) {
    const int kv0 = t * 32;
    bf16* Kd = &Ks[b][0];
    bf16* Vd = &Vs[b][0];
#pragma unroll
    for (int i2 = 0; i2 < 2; ++i2) {
      const int c = wave * 2 + i2;
      {  // K: chunk = 4 rows x 256B, 16-slot swizzle
        const int row = c * 4 + (lane >> 4);
        const int col8 = (lane & 15) ^ (row & 15);
        gl2lds16(Kh + (size_t)(kv0 + row) * DH + col8 * 8, Kd + c * 512);
      }
      {  // V: chunk = 16 rows x 64B, 4-slot swizzle
        const int row = c * 16 + (lane >> 2);
        const int s = (lane & 3) ^ ((row >> 1) & 3);
        gl2lds16(Vh + (size_t)row * SEQ + kv0 + s * 8, Vd + c * 512);
      }
    }
  };

  stage(0, 0);
  __syncthreads();

  const float ZS = RSCALE / SOFTCAP;
  const float A1 = RSCALE * L2E;
  const float B3 = -(ZS * ZS) * (1.f / 3.f);
  const float B5 = (2.f / 15.f) * (ZS * ZS) * (ZS * ZS);
  const float C  = SOFTCAP * L2E;

  for (int t = 0; t < ntiles; ++t) {
    const int cur = t & 1;
    if (t + 1 < ntiles) stage(t + 1, cur ^ 1);
    const int kv0 = t * 32;
    const bf16* Kb = &Ks[cur][0];
    const bf16* Vb = &Vs[cur][0];

    if (kv0 <= wq0 + 31) {
      // ---- QK^T (16 MFMA) ----
      f32x4 sc[2][2] = {};
      __builtin_amdgcn_s_setprio(1);
#pragma unroll
      for (int ks = 0; ks < 4; ++ks) {
        bf16x8 kf[2];
#pragma unroll
        for (int nt = 0; nt < 2; ++nt) {
          const int row = nt * 16 + rl;
          const int sl = (ks * 4 + hi) ^ (row & 15);
          kf[nt] = *(const bf16x8*)(Kb + row * 128 + sl * 8);
        }
#pragma unroll
        for (int mt = 0; mt < 2; ++mt)
#pragma unroll
          for (int nt = 0; nt < 2; ++nt)
            sc[mt][nt] = __builtin_amdgcn_mfma_f32_16x16x32_bf16(qf[mt][ks], kf[nt], sc[mt][nt], 0, 0, 0);
      }
      __builtin_amdgcn_s_setprio(0);

      // ---- fused softcap + exp (fixed max) ----
      if (kv0 < wq0) {
#pragma unroll
        for (int mt = 0; mt < 2; ++mt)
#pragma unroll
          for (int i = 0; i < 4; ++i)
#pragma unroll
            for (int nt = 0; nt < 2; ++nt) {
              const float s = sc[mt][nt][i];
              const float w = s * s;
              const float poly = fmaf(fmaf(B5, w, B3), w, 1.f);
              const float p = __builtin_amdgcn_exp2f(fmaf(s * poly, A1, -C));
              sc[mt][nt][i] = p;
              lsum[mt][i] += p;
            }
      } else {
        // diagonal tile (kv0 == wq0)
#pragma unroll
        for (int mt = 0; mt < 2; ++mt)
#pragma unroll
          for (int i = 0; i < 4; ++i) {
            const int qrow = wq0 + mt * 16 + hi * 4 + i;
#pragma unroll
            for (int nt = 0; nt < 2; ++nt) {
              const int col = kv0 + nt * 16 + rl;
              const float s = sc[mt][nt][i];
              const float w = s * s;
              const float poly = fmaf(fmaf(B5, w, B3), w, 1.f);
              float p = __builtin_amdgcn_exp2f(fmaf(s * poly, A1, -C));
              if (col > qrow) p = 0.f;
              sc[mt][nt][i] = p;
              lsum[mt][i] += p;
            }
          }
      }

      // ---- P -> LDS (bf16, 4-slot swizzle) ----
#pragma unroll
      for (int mt = 0; mt < 2; ++mt)
#pragma unroll
        for (int nt = 0; nt < 2; ++nt)
#pragma unroll
          for (int i = 0; i < 4; ++i) {
            const int r = mt * 16 + hi * 4 + i;
            const int colb = nt * 16 + rl;
            const int sl = (colb >> 3) ^ ((r >> 1) & 3);
            Ps[wave][r * 32 + sl * 8 + (colb & 7)] = (bf16)sc[mt][nt][i];
          }
      asm volatile("s_waitcnt lgkmcnt(0)" ::: "memory");
      __builtin_amdgcn_sched_barrier(0);

      // ---- PV (16 MFMA, single k-step) ----
      __builtin_amdgcn_s_setprio(1);
      bf16x8 pf[2];
#pragma unroll
      for (int mt = 0; mt < 2; ++mt) {
        const int r = mt * 16 + rl;
        const int sl = hi ^ ((r >> 1) & 3);
        pf[mt] = *(const bf16x8*)(&Ps[wave][r * 32 + sl * 8]);
      }
#pragma unroll
      for (int nt = 0; nt < 8; ++nt) {
        const int row = nt * 16 + rl;
        const int sl = hi ^ ((row >> 1) & 3);
        const bf16x8 vf = *(const bf16x8*)(Vb + row * 32 + sl * 8);
        o_acc[0][nt] = __builtin_amdgcn_mfma_f32_16x16x32_bf16(pf[0], vf, o_acc[0][nt], 0, 0, 0);
        o_acc[1][nt] = __builtin_amdgcn_mfma_f32_16x16x32_bf16(pf[1], vf, o_acc[1][nt], 0, 0, 0);
      }
      __builtin_amdgcn_s_setprio(0);
    }
    __syncthreads();
  }

  // ---- epilogue ----
#pragma unroll
  for (int mt = 0; mt < 2; ++mt)
#pragma unroll
    for (int i = 0; i < 4; ++i) {
      float l = lsum[mt][i];
#pragma unroll
      for (int m = 1; m < 16; m <<= 1) l += __shfl_xor(l, m);
      const int qrow = wq0 + mt * 16 + hi * 4 + i;
      const float inv_l = 1.f / l;
#pragma unroll
      for (int nt = 0; nt < 8; ++nt) {
        const int d = nt * 16 + rl;
        Oa[(size_t)qrow * HID + head * DH + d] = (bf16)(o_acc[mt][nt][i] * inv_l);
      }
    }
}

// ---------------------------------------------------------------------------
// host launcher
// ---------------------------------------------------------------------------
extern "C" void kernel_launch(void* const* d_in, const int* in_sizes, int n_in,
                              void* d_out, int out_size, void* d_ws, size_t ws_size,
                              hipStream_t stream)
{
  const float* hidden = (const float*)d_in[0];
  // d_in[1] = attention_mask (pure causal -1e9; implemented analytically)
  const float* cosb   = (const float*)d_in[2];
  const float* sinb   = (const float*)d_in[3];
  const float* prew   = (const float*)d_in[4];
  const float* wq     = (const float*)d_in[5];
  const float* wk     = (const float*)d_in[6];
  const float* wv     = (const float*)d_in[7];
  const float* wo     = (const float*)d_in[8];
  const float* qnw    = (const float*)d_in[9];
  const float* knw    = (const float*)d_in[10];
  float* outp = (float*)d_out;
  char* ws = (char*)d_ws;

  // workspace layout:
  bf16* wqkv = (bf16*)(ws + 0);          // 50.3 MB : [wq;wk;wv] bf16 (6144x4096); later wo bf16 (33.5 MB)
  bf16* hb   = (bf16*)(ws + 50331648);   // 16.8 MB : normed h; later q-rope (NQ,S,D)
  bf16* qkvp = (bf16*)(ws + 67108864);   // 25.2 MB : fused qkv proj (S x 6144); later attn out
  bf16* kr   = (bf16*)(ws + 92274688);   //  4.2 MB : k-rope (NKV,S,D)
  bf16* vt   = (bf16*)(ws + 96468992);   //  4.2 MB : v transposed (NKV,D,S)
  bf16* wob  = wqkv;                     // wo bf16 reuses wqkv region after QKV GEMM

  cvt3_kernel<<<4096, 256, 0, stream>>>(wq, wk, wv, wqkv,
                                        4096 * HID / 4, 1024 * HID / 4, 1024 * HID / 4);
  rmsnorm_kernel<<<SEQ, 256, 0, stream>>>(hidden, prew, hb);

  // fused QKV projection (bf16 x bf16), 768 blocks = 3/CU
  gemm_bt<false><<<dim3(NTOT / 128, SEQ / 128), 256, 0, stream>>>(
      hb, wqkv, qkvp, nullptr, nullptr, SEQ, NTOT, HID);

  cvt_kernel<<<2048, 256, 0, stream>>>(wo, wob, HID * HID / 4);   // after QKV GEMM

  qkrope_kernel<<<SEQ * (NQH + NKVH) / 4, 256, 0, stream>>>(qkvp, qnw, knw, cosb, sinb, hb, kr);
  vtrans_kernel<<<dim3(32, 4, 8), 256, 0, stream>>>(qkvp, vt);

  attn_kernel<<<dim3(16, 32), 256, 0, stream>>>(hb, kr, vt, qkvp);

  // O-proj: direct fp32 write + residual, 512 blocks
  gemm_bt<true><<<dim3(HID / 128, SEQ / 128), 256, 0, stream>>>(
      qkvp, wob, nullptr, outp, hidden, SEQ, HID, HID);
}

// Round 14
// 366.339 us; speedup vs baseline: 1.2834x; 1.2834x over previous
//
#include <hip/hip_runtime.h>
#include <cstdint>

typedef __bf16 bf16;
typedef __bf16 bf16x8 __attribute__((ext_vector_type(8)));
typedef __bf16 bf16x4 __attribute__((ext_vector_type(4)));
typedef float  f32x4  __attribute__((ext_vector_type(4)));

#define SEQ  2048
#define HID  4096
#define DH   128
#define NQH  32
#define NKVH 8
#define NTOT 6144            /* 4096 q + 1024 k + 1024 v */
#define RSCALE 0.08838834764831845f   /* 1/sqrt(128) */
#define SOFTCAP 30.0f
#define L2E 1.4426950408889634f

// async global->LDS, 16B per lane; LDS dest = wave-uniform base + lane*16
__device__ __forceinline__ void gl2lds16(const void* g, void* l) {
  __builtin_amdgcn_global_load_lds(
      (const __attribute__((address_space(1))) unsigned int*)g,
      (__attribute__((address_space(3))) unsigned int*)l, 16, 0, 0);
}

// ---------------------------------------------------------------------------
// fp32 -> bf16 conversion (single stream over [wq;wk;wv])
// ---------------------------------------------------------------------------
__global__ void cvt3_kernel(const float* __restrict__ a, const float* __restrict__ b,
                            const float* __restrict__ c, bf16* __restrict__ out,
                            int na4, int nb4, int nc4) {
  const int n = na4 + nb4 + nc4;
  const int stride = gridDim.x * blockDim.x;
  for (int i = blockIdx.x * blockDim.x + threadIdx.x; i < n; i += stride) {
    const float* src; int j;
    if (i < na4)            { src = a; j = i; }
    else if (i < na4 + nb4) { src = b; j = i - na4; }
    else                    { src = c; j = i - na4 - nb4; }
    const float4 v = ((const float4*)src)[j];
    bf16x4 o = { (bf16)v.x, (bf16)v.y, (bf16)v.z, (bf16)v.w };
    *(bf16x4*)(out + (size_t)i * 4) = o;
  }
}

__global__ void cvt_kernel(const float* __restrict__ in, bf16* __restrict__ out, int n4) {
  const int stride = gridDim.x * blockDim.x;
  for (int i = blockIdx.x * blockDim.x + threadIdx.x; i < n4; i += stride) {
    const float4 v = ((const float4*)in)[i];
    bf16x4 o = { (bf16)v.x, (bf16)v.y, (bf16)v.z, (bf16)v.w };
    *(bf16x4*)(out + (size_t)i * 4) = o;
  }
}

// ---------------------------------------------------------------------------
// pre-attention RMSNorm: (S,H) fp32 -> bf16
// ---------------------------------------------------------------------------
__global__ void rmsnorm_kernel(const float* __restrict__ x, const float* __restrict__ w,
                               bf16* __restrict__ out) {
  const int s = blockIdx.x;
  const float* xr = x + (size_t)s * HID;
  float4 v[4];
  float ss = 0.f;
#pragma unroll
  for (int j = 0; j < 4; ++j) {
    v[j] = ((const float4*)xr)[threadIdx.x + j * 256];
    ss += v[j].x * v[j].x + v[j].y * v[j].y + v[j].z * v[j].z + v[j].w * v[j].w;
  }
#pragma unroll
  for (int m = 1; m < 64; m <<= 1) ss += __shfl_xor(ss, m);
  __shared__ float red[4];
  if ((threadIdx.x & 63) == 0) red[threadIdx.x >> 6] = ss;
  __syncthreads();
  const float rn = rsqrtf((red[0] + red[1] + red[2] + red[3]) * (1.f / HID) + 1e-5f);
  bf16* orow = out + (size_t)s * HID;
#pragma unroll
  for (int j = 0; j < 4; ++j) {
    const int idx = (threadIdx.x + j * 256) * 4;
    const float4 wv = ((const float4*)w)[threadIdx.x + j * 256];
    bf16x4 o = { (bf16)(v[j].x * rn * wv.x), (bf16)(v[j].y * rn * wv.y),
                 (bf16)(v[j].z * rn * wv.z), (bf16)(v[j].w * rn * wv.w) };
    *(bf16x4*)(orow + idx) = o;
  }
}

// ---------------------------------------------------------------------------
// GEMM  C[M,N] = A[M,K] * B[N,K]^T   (R11-proven: 923 TF QKV at 3/CU)
// 128x128 tile, BK=64, 4 waves (2x2 of 64x64), 16x16x32 MFMA, 32 KB LDS.
// ---------------------------------------------------------------------------
__global__ __launch_bounds__(256, 3)
void gemm_bt(const bf16* __restrict__ A, const bf16* __restrict__ B,
             bf16* __restrict__ Cb, int M, int N, int K)
{
  __shared__ bf16 As[128 * 64];
  __shared__ bf16 Bs[128 * 64];
  const int tid  = threadIdx.x;
  const int lane = tid & 63;
  const int wave = tid >> 6;
  const int wm = wave >> 1, wn = wave & 1;

  // XCD-aware bijective swizzle (nwg % 8 == 0)
  const int gx = gridDim.x;
  const int nwg = gx * gridDim.y;
  int lin = blockIdx.x + gx * blockIdx.y;
  lin = (lin & 7) * (nwg >> 3) + (lin >> 3);
  const int m0 = (lin / gx) * 128, n0 = (lin % gx) * 128;

  f32x4 acc[4][4] = {};

  for (int kt = 0; kt < K; kt += 64) {
#pragma unroll
    for (int i = 0; i < 4; ++i) {
      const int c = wave * 4 + i;
      const int row = c * 8 + (lane >> 3);
      const int col8 = (lane & 7) ^ (row & 7);
      gl2lds16(A + (size_t)(m0 + row) * K + kt + col8 * 8, As + c * 512);
      gl2lds16(B + (size_t)(n0 + row) * K + kt + col8 * 8, Bs + c * 512);
    }
    __syncthreads();
#pragma unroll
    for (int ks = 0; ks < 2; ++ks) {
      bf16x8 af[4], bfv[4];
#pragma unroll
      for (int mi = 0; mi < 4; ++mi) {
        const int row = wm * 64 + mi * 16 + (lane & 15);
        const int slot = (ks * 4 + (lane >> 4)) ^ (row & 7);
        af[mi] = *(const bf16x8*)(As + row * 64 + slot * 8);
      }
#pragma unroll
      for (int ni = 0; ni < 4; ++ni) {
        const int row = wn * 64 + ni * 16 + (lane & 15);
        const int slot = (ks * 4 + (lane >> 4)) ^ (row & 7);
        bfv[ni] = *(const bf16x8*)(Bs + row * 64 + slot * 8);
      }
#pragma unroll
      for (int mi = 0; mi < 4; ++mi)
#pragma unroll
        for (int ni = 0; ni < 4; ++ni)
          acc[mi][ni] = __builtin_amdgcn_mfma_f32_16x16x32_bf16(af[mi], bfv[ni], acc[mi][ni], 0, 0, 0);
    }
    __syncthreads();
  }

#pragma unroll
  for (int mi = 0; mi < 4; ++mi) {
#pragma unroll
    for (int i = 0; i < 4; ++i) {
      const int m = m0 + wm * 64 + mi * 16 + (lane >> 4) * 4 + i;
#pragma unroll
      for (int ni = 0; ni < 4; ++ni) {
        const int n = n0 + wn * 64 + ni * 16 + (lane & 15);
        Cb[(size_t)m * N + n] = (bf16)acc[mi][ni][i];
      }
    }
  }
}

// ---------------------------------------------------------------------------
// Split-K GEMM (O-proj): slice z covers K in [z*Klen, (z+1)*Klen); writes
// bf16 partial to P + z*M*N. Grid 32x16x2 = 1024 blocks = 4/CU
// (32 KB LDS, 64 VGPR measured for this structure -> fits (256,4) easily).
// No atomics: each slice owns its buffer; oadd_kernel reduces.
// ---------------------------------------------------------------------------
__global__ __launch_bounds__(256, 4)
void gemm_sk(const bf16* __restrict__ A, const bf16* __restrict__ B,
             bf16* __restrict__ P, int M, int N, int K, int Klen)
{
  __shared__ bf16 As[128 * 64];
  __shared__ bf16 Bs[128 * 64];
  const int tid  = threadIdx.x;
  const int lane = tid & 63;
  const int wave = tid >> 6;
  const int wm = wave >> 1, wn = wave & 1;

  const int gx = gridDim.x;
  const int nwg = gx * gridDim.y;      // per z-slice
  int lin = blockIdx.x + gx * blockIdx.y;
  lin = (lin & 7) * (nwg >> 3) + (lin >> 3);
  const int m0 = (lin / gx) * 128, n0 = (lin % gx) * 128;
  const int k0 = blockIdx.z * Klen;
  bf16* Pz = P + (size_t)blockIdx.z * M * N;

  f32x4 acc[4][4] = {};

  for (int kt = k0; kt < k0 + Klen; kt += 64) {
#pragma unroll
    for (int i = 0; i < 4; ++i) {
      const int c = wave * 4 + i;
      const int row = c * 8 + (lane >> 3);
      const int col8 = (lane & 7) ^ (row & 7);
      gl2lds16(A + (size_t)(m0 + row) * K + kt + col8 * 8, As + c * 512);
      gl2lds16(B + (size_t)(n0 + row) * K + kt + col8 * 8, Bs + c * 512);
    }
    __syncthreads();
#pragma unroll
    for (int ks = 0; ks < 2; ++ks) {
      bf16x8 af[4], bfv[4];
#pragma unroll
      for (int mi = 0; mi < 4; ++mi) {
        const int row = wm * 64 + mi * 16 + (lane & 15);
        const int slot = (ks * 4 + (lane >> 4)) ^ (row & 7);
        af[mi] = *(const bf16x8*)(As + row * 64 + slot * 8);
      }
#pragma unroll
      for (int ni = 0; ni < 4; ++ni) {
        const int row = wn * 64 + ni * 16 + (lane & 15);
        const int slot = (ks * 4 + (lane >> 4)) ^ (row & 7);
        bfv[ni] = *(const bf16x8*)(Bs + row * 64 + slot * 8);
      }
#pragma unroll
      for (int mi = 0; mi < 4; ++mi)
#pragma unroll
        for (int ni = 0; ni < 4; ++ni)
          acc[mi][ni] = __builtin_amdgcn_mfma_f32_16x16x32_bf16(af[mi], bfv[ni], acc[mi][ni], 0, 0, 0);
    }
    __syncthreads();
  }

#pragma unroll
  for (int mi = 0; mi < 4; ++mi) {
#pragma unroll
    for (int i = 0; i < 4; ++i) {
      const int m = m0 + wm * 64 + mi * 16 + (lane >> 4) * 4 + i;
#pragma unroll
      for (int ni = 0; ni < 4; ++ni) {
        const int n = n0 + wn * 64 + ni * 16 + (lane & 15);
        Pz[(size_t)m * N + n] = (bf16)acc[mi][ni][i];
      }
    }
  }
}

// ---------------------------------------------------------------------------
// O-proj reduce: out = P0 + P1 + residual (fp32)
// ---------------------------------------------------------------------------
__global__ void oadd_kernel(const bf16* __restrict__ P0, const bf16* __restrict__ P1,
                            const float* __restrict__ resid, float* __restrict__ out,
                            int n4) {
  const int stride = gridDim.x * blockDim.x;
  for (int i = blockIdx.x * blockDim.x + threadIdx.x; i < n4; i += stride) {
    const bf16x4 a = ((const bf16x4*)P0)[i];
    const bf16x4 b = ((const bf16x4*)P1)[i];
    const float4 r = ((const float4*)resid)[i];
    float4 o;
    o.x = r.x + (float)a[0] + (float)b[0];
    o.y = r.y + (float)a[1] + (float)b[1];
    o.z = r.z + (float)a[2] + (float)b[2];
    o.w = r.w + (float)a[3] + (float)b[3];
    ((float4*)out)[i] = o;
  }
}

// ---------------------------------------------------------------------------
// QK RMSNorm + RoPE; one wave per (s, head). reads fused qkv proj (S x 6144).
// ---------------------------------------------------------------------------
__global__ void qkrope_kernel(const bf16* __restrict__ qkv,
                              const float* __restrict__ qw, const float* __restrict__ kw,
                              const float* __restrict__ cs, const float* __restrict__ sn,
                              bf16* __restrict__ qr, bf16* __restrict__ kr)
{
  const int w = blockIdx.x * 4 + (threadIdx.x >> 6);
  const int lane = threadIdx.x & 63;
  const int s = w / (NQH + NKVH);
  const int hh = w % (NQH + NKVH);
  const bf16* src; bf16* dst; const float* nw;
  if (hh < NQH) {
    src = qkv + (size_t)s * NTOT + hh * DH;
    dst = qr + ((size_t)hh * SEQ + s) * DH;
    nw = qw;
  } else {
    const int h2 = hh - NQH;
    src = qkv + (size_t)s * NTOT + 4096 + h2 * DH;
    dst = kr + ((size_t)h2 * SEQ + s) * DH;
    nw = kw;
  }
  const float x0 = (float)src[lane], x1 = (float)src[lane + 64];
  float ss = x0 * x0 + x1 * x1;
#pragma unroll
  for (int m = 1; m < 64; m <<= 1) ss += __shfl_xor(ss, m);
  const float rn = rsqrtf(ss * (1.f / DH) + 1e-5f);
  const float n0 = x0 * rn * nw[lane], n1 = x1 * rn * nw[lane + 64];
  const float c0 = cs[s * DH + lane],      s0 = sn[s * DH + lane];
  const float c1 = cs[s * DH + lane + 64], s1 = sn[s * DH + lane + 64];
  dst[lane]      = (bf16)(n0 * c0 - n1 * s0);
  dst[lane + 64] = (bf16)(n1 * c1 + n0 * s1);
}

// ---------------------------------------------------------------------------
// V transpose: fused qkv (S, 6144; v at col 5120+h*128) -> (NKV, D, S)
// ---------------------------------------------------------------------------
__global__ void vtrans_kernel(const bf16* __restrict__ qkv, bf16* __restrict__ vt)
{
  __shared__ bf16 tbuf[64][33];
  const int s0 = blockIdx.x * 64;
  const int d0 = blockIdx.y * 32;
  const int h  = blockIdx.z;
  const int tid = threadIdx.x;
  {
    const int col = tid & 31, r0 = tid >> 5;
    for (int r = r0; r < 64; r += 8)
      tbuf[r][col] = qkv[(size_t)(s0 + r) * NTOT + 5120 + h * DH + d0 + col];
  }
  __syncthreads();
  {
    const int sc = tid & 63, dr0 = tid >> 6;
    for (int d = dr0; d < 32; d += 4)
      vt[((size_t)h * DH + d0 + d) * SEQ + s0 + sc] = tbuf[sc][d];
  }
}

// ---------------------------------------------------------------------------
// Flash attention, causal + softcap, GQA (exact R11 kernel: KVBLK=64, 80 KB
// LDS, 2 blocks/CU, 128 VGPR, no spills - measured 91 us).
// ---------------------------------------------------------------------------
__global__ __launch_bounds__(256, 2)
void attn_kernel(const bf16* __restrict__ Q, const bf16* __restrict__ Kr,
                 const bf16* __restrict__ Vt, bf16* __restrict__ Oa)
{
  __shared__ bf16 Ks[2][64 * 128];  // [kv][d], 16-slot swizzle
  __shared__ bf16 Vs[2][128 * 64];  // [d][kv], 8-slot swizzle
  __shared__ bf16 Ps[4][32 * 64];   // per-wave P, 8-slot swizzle

  const int tid = threadIdx.x, lane = tid & 63, wave = tid >> 6;

  // balanced (bx, head) remap
  const int lin  = blockIdx.x + 16 * blockIdx.y;
  const int slot = lin >> 8, idx = lin & 255;
  const int bx   = slot ? (15 - (idx & 15)) : (idx & 15);
  const int head = (slot << 4) | (idx >> 4);
  const int kvh  = head >> 2;
  const int q0   = bx * 128;
  const int wq0  = q0 + wave * 32;

  const bf16* Qh = Q  + (size_t)head * SEQ * DH;
  const bf16* Kh = Kr + (size_t)kvh * SEQ * DH;
  const bf16* Vh = Vt + (size_t)kvh * DH * SEQ;

  bf16x8 qf[2][4];
#pragma unroll
  for (int mt = 0; mt < 2; ++mt)
#pragma unroll
    for (int kc = 0; kc < 4; ++kc) {
      const int r = wq0 + mt * 16 + (lane & 15);
      qf[mt][kc] = *(const bf16x8*)(Qh + (size_t)r * DH + kc * 32 + (lane >> 4) * 8);
    }

  float lsum[2][4] = {};
  f32x4 o_acc[2][8] = {};

  const int ntiles = q0 / 64 + 2;

  auto stage = [&](int t, int b) {
    const int kv0 = t * 64;
    bf16* Kd = &Ks[b][0];
    bf16* Vd = &Vs[b][0];
#pragma unroll
    for (int i2 = 0; i2 < 4; ++i2) {
      const int c = wave * 4 + i2;
      {
        const int row = c * 4 + (lane >> 4);
        const int col8 = (lane & 15) ^ (row & 15);
        gl2lds16(Kh + (size_t)(kv0 + row) * DH + col8 * 8, Kd + c * 512);
      }
      {
        const int row = c * 8 + (lane >> 3);
        const int col8 = (lane & 7) ^ (row & 7);
        gl2lds16(Vh + (size_t)row * SEQ + kv0 + col8 * 8, Vd + c * 512);
      }
    }
  };

  stage(0, 0);
  __syncthreads();

  const float ZS = RSCALE / SOFTCAP;
  const float A1 = RSCALE * L2E;
  const float B3 = -(ZS * ZS) * (1.f / 3.f);
  const float B5 = (2.f / 15.f) * (ZS * ZS) * (ZS * ZS);
  const float C  = SOFTCAP * L2E;

  for (int t = 0; t < ntiles; ++t) {
    const int cur = t & 1;
    if (t + 1 < ntiles) stage(t + 1, cur ^ 1);
    const int kv0 = t * 64;
    const bf16* Kb = &Ks[cur][0];
    const bf16* Vb = &Vs[cur][0];

    if (kv0 <= wq0 + 31) {
      f32x4 sc[2][4] = {};
      __builtin_amdgcn_s_setprio(1);
#pragma unroll
      for (int ks = 0; ks < 4; ++ks) {
        bf16x8 kf[4];
#pragma unroll
        for (int nt = 0; nt < 4; ++nt) {
          const int row = nt * 16 + (lane & 15);
          const int sl = (ks * 4 + (lane >> 4)) ^ (row & 15);
          kf[nt] = *(const bf16x8*)(Kb + row * 128 + sl * 8);
        }
#pragma unroll
        for (int mt = 0; mt < 2; ++mt)
#pragma unroll
          for (int nt = 0; nt < 4; ++nt)
            sc[mt][nt] = __builtin_amdgcn_mfma_f32_16x16x32_bf16(qf[mt][ks], kf[nt], sc[mt][nt], 0, 0, 0);
      }
      __builtin_amdgcn_s_setprio(0);

      if (kv0 + 63 <= wq0) {
#pragma unroll
        for (int mt = 0; mt < 2; ++mt)
#pragma unroll
          for (int i = 0; i < 4; ++i)
#pragma unroll
            for (int nt = 0; nt < 4; ++nt) {
              const float s = sc[mt][nt][i];
              const float w = s * s;
              const float poly = fmaf(fmaf(B5, w, B3), w, 1.f);
              const float p = __builtin_amdgcn_exp2f(fmaf(s * poly, A1, -C));
              sc[mt][nt][i] = p;
              lsum[mt][i] += p;
            }
      } else {
#pragma unroll
        for (int mt = 0; mt < 2; ++mt)
#pragma unroll
          for (int i = 0; i < 4; ++i) {
            const int qrow = wq0 + mt * 16 + (lane >> 4) * 4 + i;
#pragma unroll
            for (int nt = 0; nt < 4; ++nt) {
              const int col = kv0 + nt * 16 + (lane & 15);
              const float s = sc[mt][nt][i];
              const float w = s * s;
              const float poly = fmaf(fmaf(B5, w, B3), w, 1.f);
              float p = __builtin_amdgcn_exp2f(fmaf(s * poly, A1, -C));
              if (col > qrow) p = 0.f;
              sc[mt][nt][i] = p;
              lsum[mt][i] += p;
            }
          }
      }

#pragma unroll
      for (int mt = 0; mt < 2; ++mt)
#pragma unroll
        for (int nt = 0; nt < 4; ++nt)
#pragma unroll
          for (int i = 0; i < 4; ++i) {
            const int r = mt * 16 + (lane >> 4) * 4 + i;
            const int colb = nt * 16 + (lane & 15);
            const int sl = (colb >> 3) ^ (r & 7);
            Ps[wave][r * 64 + sl * 8 + (colb & 7)] = (bf16)sc[mt][nt][i];
          }
      asm volatile("s_waitcnt lgkmcnt(0)" ::: "memory");
      __builtin_amdgcn_sched_barrier(0);

      __builtin_amdgcn_s_setprio(1);
#pragma unroll
      for (int ks2 = 0; ks2 < 2; ++ks2) {
        bf16x8 pf[2];
#pragma unroll
        for (int mt = 0; mt < 2; ++mt) {
          const int r = mt * 16 + (lane & 15);
          const int sl = (ks2 * 4 + (lane >> 4)) ^ (r & 7);
          pf[mt] = *(const bf16x8*)(&Ps[wave][r * 64 + sl * 8]);
        }
#pragma unroll
        for (int nt = 0; nt < 8; ++nt) {
          const int row = nt * 16 + (lane & 15);
          const int sl = (ks2 * 4 + (lane >> 4)) ^ (row & 7);
          const bf16x8 vf = *(const bf16x8*)(Vb + row * 64 + sl * 8);
          o_acc[0][nt] = __builtin_amdgcn_mfma_f32_16x16x32_bf16(pf[0], vf, o_acc[0][nt], 0, 0, 0);
          o_acc[1][nt] = __builtin_amdgcn_mfma_f32_16x16x32_bf16(pf[1], vf, o_acc[1][nt], 0, 0, 0);
        }
      }
      __builtin_amdgcn_s_setprio(0);
    }
    __syncthreads();
  }

#pragma unroll
  for (int mt = 0; mt < 2; ++mt)
#pragma unroll
    for (int i = 0; i < 4; ++i) {
      float l = lsum[mt][i];
#pragma unroll
      for (int m = 1; m < 16; m <<= 1) l += __shfl_xor(l, m);
      const int qrow = wq0 + mt * 16 + (lane >> 4) * 4 + i;
      const float inv_l = 1.f / l;
#pragma unroll
      for (int nt = 0; nt < 8; ++nt) {
        const int d = nt * 16 + (lane & 15);
        Oa[(size_t)qrow * HID + head * DH + d] = (bf16)(o_acc[mt][nt][i] * inv_l);
      }
    }
}

// ---------------------------------------------------------------------------
// host launcher
// ---------------------------------------------------------------------------
extern "C" void kernel_launch(void* const* d_in, const int* in_sizes, int n_in,
                              void* d_out, int out_size, void* d_ws, size_t ws_size,
                              hipStream_t stream)
{
  const float* hidden = (const float*)d_in[0];
  // d_in[1] = attention_mask (pure causal -1e9; implemented analytically)
  const float* cosb   = (const float*)d_in[2];
  const float* sinb   = (const float*)d_in[3];
  const float* prew   = (const float*)d_in[4];
  const float* wq     = (const float*)d_in[5];
  const float* wk     = (const float*)d_in[6];
  const float* wv     = (const float*)d_in[7];
  const float* wo     = (const float*)d_in[8];
  const float* qnw    = (const float*)d_in[9];
  const float* knw    = (const float*)d_in[10];
  float* outp = (float*)d_out;
  char* ws = (char*)d_ws;

  // workspace layout (regions reused once their tenant is dead):
  bf16* wqkv = (bf16*)(ws + 0);          // 50.3 MB : [wq;wk;wv] bf16 (6144x4096)
  bf16* wob  = wqkv;                     // wo bf16 (33.5 MB), reuses wqkv after QKV GEMM
  bf16* p0   = (bf16*)(ws + 33554432);   // 16.8 MB : O-proj partial z=0 (wqkv rows 4096+, dead after QKV)
  bf16* hb   = (bf16*)(ws + 50331648);   // 16.8 MB : normed h; later q-rope; later O-proj partial z=1
  bf16* p1   = hb;                       //           (hb dead after attn)
  bf16* qkvp = (bf16*)(ws + 67108864);   // 25.2 MB : fused qkv proj (S x 6144); later attn out
  bf16* kr   = (bf16*)(ws + 92274688);   //  4.2 MB : k-rope (NKV,S,D)
  bf16* vt   = (bf16*)(ws + 96468992);   //  4.2 MB : v transposed (NKV,D,S)

  cvt3_kernel<<<4096, 256, 0, stream>>>(wq, wk, wv, wqkv,
                                        4096 * HID / 4, 1024 * HID / 4, 1024 * HID / 4);
  rmsnorm_kernel<<<SEQ, 256, 0, stream>>>(hidden, prew, hb);

  // fused QKV projection (bf16 x bf16), 768 blocks = 3/CU
  gemm_bt<<<dim3(NTOT / 128, SEQ / 128), 256, 0, stream>>>(
      hb, wqkv, qkvp, SEQ, NTOT, HID);

  cvt_kernel<<<2048, 256, 0, stream>>>(wo, wob, HID * HID / 4);   // after QKV GEMM

  qkrope_kernel<<<SEQ * (NQH + NKVH) / 4, 256, 0, stream>>>(qkvp, qnw, knw, cosb, sinb, hb, kr);
  vtrans_kernel<<<dim3(32, 4, 8), 256, 0, stream>>>(qkvp, vt);

  attn_kernel<<<dim3(16, 32), 256, 0, stream>>>(hb, kr, vt, qkvp);

  // O-proj: split-K=2, 1024 blocks = 4/CU, bf16 partials (no atomics)
  gemm_sk<<<dim3(HID / 128, SEQ / 128, 2), 256, 0, stream>>>(
      qkvp, wob, p0, SEQ, HID, HID, HID / 2);
  oadd_kernel<<<2048, 256, 0, stream>>>(p0, p1, hidden, outp, SEQ * HID / 4);
}

// Round 15
// 354.439 us; speedup vs baseline: 1.3265x; 1.0336x over previous
//
#include <hip/hip_runtime.h>
#include <cstdint>

typedef __bf16 bf16;
typedef __bf16 bf16x8 __attribute__((ext_vector_type(8)));
typedef __bf16 bf16x4 __attribute__((ext_vector_type(4)));
typedef float  f32x4  __attribute__((ext_vector_type(4)));

#define SEQ  2048
#define HID  4096
#define DH   128
#define NQH  32
#define NKVH 8
#define NTOT 6144            /* 4096 q + 1024 k + 1024 v */
#define RSCALE 0.08838834764831845f   /* 1/sqrt(128) */
#define SOFTCAP 30.0f
#define L2E 1.4426950408889634f

// async global->LDS, 16B per lane; LDS dest = wave-uniform base + lane*16
__device__ __forceinline__ void gl2lds16(const void* g, void* l) {
  __builtin_amdgcn_global_load_lds(
      (const __attribute__((address_space(1))) unsigned int*)g,
      (__attribute__((address_space(3))) unsigned int*)l, 16, 0, 0);
}

// ---------------------------------------------------------------------------
// fp32 -> bf16 conversion (single stream over [wq;wk;wv])
// ---------------------------------------------------------------------------
__global__ void cvt3_kernel(const float* __restrict__ a, const float* __restrict__ b,
                            const float* __restrict__ c, bf16* __restrict__ out,
                            int na4, int nb4, int nc4) {
  const int n = na4 + nb4 + nc4;
  const int stride = gridDim.x * blockDim.x;
  for (int i = blockIdx.x * blockDim.x + threadIdx.x; i < n; i += stride) {
    const float* src; int j;
    if (i < na4)            { src = a; j = i; }
    else if (i < na4 + nb4) { src = b; j = i - na4; }
    else                    { src = c; j = i - na4 - nb4; }
    const float4 v = ((const float4*)src)[j];
    bf16x4 o = { (bf16)v.x, (bf16)v.y, (bf16)v.z, (bf16)v.w };
    *(bf16x4*)(out + (size_t)i * 4) = o;
  }
}

__global__ void cvt_kernel(const float* __restrict__ in, bf16* __restrict__ out, int n4) {
  const int stride = gridDim.x * blockDim.x;
  for (int i = blockIdx.x * blockDim.x + threadIdx.x; i < n4; i += stride) {
    const float4 v = ((const float4*)in)[i];
    bf16x4 o = { (bf16)v.x, (bf16)v.y, (bf16)v.z, (bf16)v.w };
    *(bf16x4*)(out + (size_t)i * 4) = o;
  }
}

// ---------------------------------------------------------------------------
// pre-attention RMSNorm: (S,H) fp32 -> bf16
// ---------------------------------------------------------------------------
__global__ void rmsnorm_kernel(const float* __restrict__ x, const float* __restrict__ w,
                               bf16* __restrict__ out) {
  const int s = blockIdx.x;
  const float* xr = x + (size_t)s * HID;
  float4 v[4];
  float ss = 0.f;
#pragma unroll
  for (int j = 0; j < 4; ++j) {
    v[j] = ((const float4*)xr)[threadIdx.x + j * 256];
    ss += v[j].x * v[j].x + v[j].y * v[j].y + v[j].z * v[j].z + v[j].w * v[j].w;
  }
#pragma unroll
  for (int m = 1; m < 64; m <<= 1) ss += __shfl_xor(ss, m);
  __shared__ float red[4];
  if ((threadIdx.x & 63) == 0) red[threadIdx.x >> 6] = ss;
  __syncthreads();
  const float rn = rsqrtf((red[0] + red[1] + red[2] + red[3]) * (1.f / HID) + 1e-5f);
  bf16* orow = out + (size_t)s * HID;
#pragma unroll
  for (int j = 0; j < 4; ++j) {
    const int idx = (threadIdx.x + j * 256) * 4;
    const float4 wv = ((const float4*)w)[threadIdx.x + j * 256];
    bf16x4 o = { (bf16)(v[j].x * rn * wv.x), (bf16)(v[j].y * rn * wv.y),
                 (bf16)(v[j].z * rn * wv.z), (bf16)(v[j].w * rn * wv.w) };
    *(bf16x4*)(orow + idx) = o;
  }
}

// ---------------------------------------------------------------------------
// GEMM  C[M,N] = A[M,K] * B[N,K]^T   (R11-proven: 923 TF QKV at 3/CU)
// 128x128 tile, BK=64, 4 waves (2x2 of 64x64), 16x16x32 MFMA, 32 KB LDS.
// LDS XOR-swizzled via pre-swizzled global_load_lds source. XCD-aware grid.
// ---------------------------------------------------------------------------
template<bool FINAL>
__global__ __launch_bounds__(256, 3)
void gemm_bt(const bf16* __restrict__ A, const bf16* __restrict__ B,
             bf16* __restrict__ Cb, float* __restrict__ Cf,
             const float* __restrict__ resid, int M, int N, int K)
{
  __shared__ bf16 As[128 * 64];
  __shared__ bf16 Bs[128 * 64];
  const int tid  = threadIdx.x;
  const int lane = tid & 63;
  const int wave = tid >> 6;
  const int wm = wave >> 1, wn = wave & 1;

  // XCD-aware bijective swizzle (nwg % 8 == 0 for all our launches)
  const int gx = gridDim.x;
  const int nwg = gx * gridDim.y;
  int lin = blockIdx.x + gx * blockIdx.y;
  lin = (lin & 7) * (nwg >> 3) + (lin >> 3);
  const int m0 = (lin / gx) * 128, n0 = (lin % gx) * 128;

  f32x4 acc[4][4] = {};

  for (int kt = 0; kt < K; kt += 64) {
#pragma unroll
    for (int i = 0; i < 4; ++i) {
      const int c = wave * 4 + i;
      const int row = c * 8 + (lane >> 3);
      const int col8 = (lane & 7) ^ (row & 7);
      gl2lds16(A + (size_t)(m0 + row) * K + kt + col8 * 8, As + c * 512);
      gl2lds16(B + (size_t)(n0 + row) * K + kt + col8 * 8, Bs + c * 512);
    }
    __syncthreads();
#pragma unroll
    for (int ks = 0; ks < 2; ++ks) {
      bf16x8 af[4], bfv[4];
#pragma unroll
      for (int mi = 0; mi < 4; ++mi) {
        const int row = wm * 64 + mi * 16 + (lane & 15);
        const int slot = (ks * 4 + (lane >> 4)) ^ (row & 7);
        af[mi] = *(const bf16x8*)(As + row * 64 + slot * 8);
      }
#pragma unroll
      for (int ni = 0; ni < 4; ++ni) {
        const int row = wn * 64 + ni * 16 + (lane & 15);
        const int slot = (ks * 4 + (lane >> 4)) ^ (row & 7);
        bfv[ni] = *(const bf16x8*)(Bs + row * 64 + slot * 8);
      }
#pragma unroll
      for (int mi = 0; mi < 4; ++mi)
#pragma unroll
        for (int ni = 0; ni < 4; ++ni)
          acc[mi][ni] = __builtin_amdgcn_mfma_f32_16x16x32_bf16(af[mi], bfv[ni], acc[mi][ni], 0, 0, 0);
    }
    __syncthreads();
  }

#pragma unroll
  for (int mi = 0; mi < 4; ++mi) {
#pragma unroll
    for (int i = 0; i < 4; ++i) {
      const int m = m0 + wm * 64 + mi * 16 + (lane >> 4) * 4 + i;
#pragma unroll
      for (int ni = 0; ni < 4; ++ni) {
        const int n = n0 + wn * 64 + ni * 16 + (lane & 15);
        const float v = acc[mi][ni][i];
        if constexpr (FINAL) {
          Cf[(size_t)m * N + n] = v + resid[(size_t)m * N + n];
        } else {
          Cb[(size_t)m * N + n] = (bf16)v;
        }
      }
    }
  }
}

// ---------------------------------------------------------------------------
// QK RMSNorm + RoPE; one wave per (s, head). reads fused qkv proj (S x 6144).
// ---------------------------------------------------------------------------
__global__ void qkrope_kernel(const bf16* __restrict__ qkv,
                              const float* __restrict__ qw, const float* __restrict__ kw,
                              const float* __restrict__ cs, const float* __restrict__ sn,
                              bf16* __restrict__ qr, bf16* __restrict__ kr)
{
  const int w = blockIdx.x * 4 + (threadIdx.x >> 6);
  const int lane = threadIdx.x & 63;
  const int s = w / (NQH + NKVH);
  const int hh = w % (NQH + NKVH);
  const bf16* src; bf16* dst; const float* nw;
  if (hh < NQH) {
    src = qkv + (size_t)s * NTOT + hh * DH;
    dst = qr + ((size_t)hh * SEQ + s) * DH;
    nw = qw;
  } else {
    const int h2 = hh - NQH;
    src = qkv + (size_t)s * NTOT + 4096 + h2 * DH;
    dst = kr + ((size_t)h2 * SEQ + s) * DH;
    nw = kw;
  }
  const float x0 = (float)src[lane], x1 = (float)src[lane + 64];
  float ss = x0 * x0 + x1 * x1;
#pragma unroll
  for (int m = 1; m < 64; m <<= 1) ss += __shfl_xor(ss, m);
  const float rn = rsqrtf(ss * (1.f / DH) + 1e-5f);
  const float n0 = x0 * rn * nw[lane], n1 = x1 * rn * nw[lane + 64];
  const float c0 = cs[s * DH + lane],      s0 = sn[s * DH + lane];
  const float c1 = cs[s * DH + lane + 64], s1 = sn[s * DH + lane + 64];
  dst[lane]      = (bf16)(n0 * c0 - n1 * s0);
  dst[lane + 64] = (bf16)(n1 * c1 + n0 * s1);
}

// ---------------------------------------------------------------------------
// V transpose: fused qkv (S, 6144; v at col 5120+h*128) -> (NKV, D, S)
// ---------------------------------------------------------------------------
__global__ void vtrans_kernel(const bf16* __restrict__ qkv, bf16* __restrict__ vt)
{
  __shared__ bf16 tbuf[64][33];
  const int s0 = blockIdx.x * 64;
  const int d0 = blockIdx.y * 32;
  const int h  = blockIdx.z;
  const int tid = threadIdx.x;
  {
    const int col = tid & 31, r0 = tid >> 5;
    for (int r = r0; r < 64; r += 8)
      tbuf[r][col] = qkv[(size_t)(s0 + r) * NTOT + 5120 + h * DH + d0 + col];
  }
  __syncthreads();
  {
    const int sc = tid & 63, dr0 = tid >> 6;
    for (int d = dr0; d < 32; d += 4)
      vt[((size_t)h * DH + d0 + d) * SEQ + s0 + sc] = tbuf[sc][d];
  }
}

// ---------------------------------------------------------------------------
// Flash attention, causal + softcap, GQA (exact R11 kernel: KVBLK=64, 80 KB
// LDS, 2 blocks/CU, 128 VGPR, no spills - measured 91 us).
// Fixed-max softmax: p = exp2(A1*s*(1+w*(B3+B5*w)) - C), w = s*s.
// ---------------------------------------------------------------------------
__global__ __launch_bounds__(256, 2)
void attn_kernel(const bf16* __restrict__ Q, const bf16* __restrict__ Kr,
                 const bf16* __restrict__ Vt, bf16* __restrict__ Oa)
{
  __shared__ bf16 Ks[2][64 * 128];  // [kv][d], 16-slot swizzle
  __shared__ bf16 Vs[2][128 * 64];  // [d][kv], 8-slot swizzle
  __shared__ bf16 Ps[4][32 * 64];   // per-wave P, 8-slot swizzle

  const int tid = threadIdx.x, lane = tid & 63, wave = tid >> 6;

  // balanced (bx, head) remap
  const int lin  = blockIdx.x + 16 * blockIdx.y;
  const int slot = lin >> 8, idx = lin & 255;
  const int bx   = slot ? (15 - (idx & 15)) : (idx & 15);
  const int head = (slot << 4) | (idx >> 4);
  const int kvh  = head >> 2;
  const int q0   = bx * 128;
  const int wq0  = q0 + wave * 32;

  const bf16* Qh = Q  + (size_t)head * SEQ * DH;
  const bf16* Kh = Kr + (size_t)kvh * SEQ * DH;
  const bf16* Vh = Vt + (size_t)kvh * DH * SEQ;

  bf16x8 qf[2][4];
#pragma unroll
  for (int mt = 0; mt < 2; ++mt)
#pragma unroll
    for (int kc = 0; kc < 4; ++kc) {
      const int r = wq0 + mt * 16 + (lane & 15);
      qf[mt][kc] = *(const bf16x8*)(Qh + (size_t)r * DH + kc * 32 + (lane >> 4) * 8);
    }

  float lsum[2][4] = {};
  f32x4 o_acc[2][8] = {};

  const int ntiles = q0 / 64 + 2;

  auto stage = [&](int t, int b) {
    const int kv0 = t * 64;
    bf16* Kd = &Ks[b][0];
    bf16* Vd = &Vs[b][0];
#pragma unroll
    for (int i2 = 0; i2 < 4; ++i2) {
      const int c = wave * 4 + i2;
      {
        const int row = c * 4 + (lane >> 4);
        const int col8 = (lane & 15) ^ (row & 15);
        gl2lds16(Kh + (size_t)(kv0 + row) * DH + col8 * 8, Kd + c * 512);
      }
      {
        const int row = c * 8 + (lane >> 3);
        const int col8 = (lane & 7) ^ (row & 7);
        gl2lds16(Vh + (size_t)row * SEQ + kv0 + col8 * 8, Vd + c * 512);
      }
    }
  };

  stage(0, 0);
  __syncthreads();

  const float ZS = RSCALE / SOFTCAP;
  const float A1 = RSCALE * L2E;
  const float B3 = -(ZS * ZS) * (1.f / 3.f);
  const float B5 = (2.f / 15.f) * (ZS * ZS) * (ZS * ZS);
  const float C  = SOFTCAP * L2E;

  for (int t = 0; t < ntiles; ++t) {
    const int cur = t & 1;
    if (t + 1 < ntiles) stage(t + 1, cur ^ 1);
    const int kv0 = t * 64;
    const bf16* Kb = &Ks[cur][0];
    const bf16* Vb = &Vs[cur][0];

    if (kv0 <= wq0 + 31) {
      f32x4 sc[2][4] = {};
      __builtin_amdgcn_s_setprio(1);
#pragma unroll
      for (int ks = 0; ks < 4; ++ks) {
        bf16x8 kf[4];
#pragma unroll
        for (int nt = 0; nt < 4; ++nt) {
          const int row = nt * 16 + (lane & 15);
          const int sl = (ks * 4 + (lane >> 4)) ^ (row & 15);
          kf[nt] = *(const bf16x8*)(Kb + row * 128 + sl * 8);
        }
#pragma unroll
        for (int mt = 0; mt < 2; ++mt)
#pragma unroll
          for (int nt = 0; nt < 4; ++nt)
            sc[mt][nt] = __builtin_amdgcn_mfma_f32_16x16x32_bf16(qf[mt][ks], kf[nt], sc[mt][nt], 0, 0, 0);
      }
      __builtin_amdgcn_s_setprio(0);

      if (kv0 + 63 <= wq0) {
#pragma unroll
        for (int mt = 0; mt < 2; ++mt)
#pragma unroll
          for (int i = 0; i < 4; ++i)
#pragma unroll
            for (int nt = 0; nt < 4; ++nt) {
              const float s = sc[mt][nt][i];
              const float w = s * s;
              const float poly = fmaf(fmaf(B5, w, B3), w, 1.f);
              const float p = __builtin_amdgcn_exp2f(fmaf(s * poly, A1, -C));
              sc[mt][nt][i] = p;
              lsum[mt][i] += p;
            }
      } else {
#pragma unroll
        for (int mt = 0; mt < 2; ++mt)
#pragma unroll
          for (int i = 0; i < 4; ++i) {
            const int qrow = wq0 + mt * 16 + (lane >> 4) * 4 + i;
#pragma unroll
            for (int nt = 0; nt < 4; ++nt) {
              const int col = kv0 + nt * 16 + (lane & 15);
              const float s = sc[mt][nt][i];
              const float w = s * s;
              const float poly = fmaf(fmaf(B5, w, B3), w, 1.f);
              float p = __builtin_amdgcn_exp2f(fmaf(s * poly, A1, -C));
              if (col > qrow) p = 0.f;
              sc[mt][nt][i] = p;
              lsum[mt][i] += p;
            }
          }
      }

#pragma unroll
      for (int mt = 0; mt < 2; ++mt)
#pragma unroll
        for (int nt = 0; nt < 4; ++nt)
#pragma unroll
          for (int i = 0; i < 4; ++i) {
            const int r = mt * 16 + (lane >> 4) * 4 + i;
            const int colb = nt * 16 + (lane & 15);
            const int sl = (colb >> 3) ^ (r & 7);
            Ps[wave][r * 64 + sl * 8 + (colb & 7)] = (bf16)sc[mt][nt][i];
          }
      asm volatile("s_waitcnt lgkmcnt(0)" ::: "memory");
      __builtin_amdgcn_sched_barrier(0);

      __builtin_amdgcn_s_setprio(1);
#pragma unroll
      for (int ks2 = 0; ks2 < 2; ++ks2) {
        bf16x8 pf[2];
#pragma unroll
        for (int mt = 0; mt < 2; ++mt) {
          const int r = mt * 16 + (lane & 15);
          const int sl = (ks2 * 4 + (lane >> 4)) ^ (r & 7);
          pf[mt] = *(const bf16x8*)(&Ps[wave][r * 64 + sl * 8]);
        }
#pragma unroll
        for (int nt = 0; nt < 8; ++nt) {
          const int row = nt * 16 + (lane & 15);
          const int sl = (ks2 * 4 + (lane >> 4)) ^ (row & 7);
          const bf16x8 vf = *(const bf16x8*)(Vb + row * 64 + sl * 8);
          o_acc[0][nt] = __builtin_amdgcn_mfma_f32_16x16x32_bf16(pf[0], vf, o_acc[0][nt], 0, 0, 0);
          o_acc[1][nt] = __builtin_amdgcn_mfma_f32_16x16x32_bf16(pf[1], vf, o_acc[1][nt], 0, 0, 0);
        }
      }
      __builtin_amdgcn_s_setprio(0);
    }
    __syncthreads();
  }

#pragma unroll
  for (int mt = 0; mt < 2; ++mt)
#pragma unroll
    for (int i = 0; i < 4; ++i) {
      float l = lsum[mt][i];
#pragma unroll
      for (int m = 1; m < 16; m <<= 1) l += __shfl_xor(l, m);
      const int qrow = wq0 + mt * 16 + (lane >> 4) * 4 + i;
      const float inv_l = 1.f / l;
#pragma unroll
      for (int nt = 0; nt < 8; ++nt) {
        const int d = nt * 16 + (lane & 15);
        Oa[(size_t)qrow * HID + head * DH + d] = (bf16)(o_acc[mt][nt][i] * inv_l);
      }
    }
}

// ---------------------------------------------------------------------------
// host launcher
// ---------------------------------------------------------------------------
extern "C" void kernel_launch(void* const* d_in, const int* in_sizes, int n_in,
                              void* d_out, int out_size, void* d_ws, size_t ws_size,
                              hipStream_t stream)
{
  const float* hidden = (const float*)d_in[0];
  // d_in[1] = attention_mask (pure causal -1e9; implemented analytically)
  const float* cosb   = (const float*)d_in[2];
  const float* sinb   = (const float*)d_in[3];
  const float* prew   = (const float*)d_in[4];
  const float* wq     = (const float*)d_in[5];
  const float* wk     = (const float*)d_in[6];
  const float* wv     = (const float*)d_in[7];
  const float* wo     = (const float*)d_in[8];
  const float* qnw    = (const float*)d_in[9];
  const float* knw    = (const float*)d_in[10];
  float* outp = (float*)d_out;
  char* ws = (char*)d_ws;

  // workspace layout:
  bf16* wqkv = (bf16*)(ws + 0);          // 50.3 MB : [wq;wk;wv] bf16 (6144x4096); later wo bf16 (33.5 MB)
  bf16* hb   = (bf16*)(ws + 50331648);   // 16.8 MB : normed h; later q-rope (NQ,S,D)
  bf16* qkvp = (bf16*)(ws + 67108864);   // 25.2 MB : fused qkv proj (S x 6144); later attn out
  bf16* kr   = (bf16*)(ws + 92274688);   //  4.2 MB : k-rope (NKV,S,D)
  bf16* vt   = (bf16*)(ws + 96468992);   //  4.2 MB : v transposed (NKV,D,S)
  bf16* wob  = wqkv;                     // wo bf16 reuses wqkv region after QKV GEMM

  cvt3_kernel<<<4096, 256, 0, stream>>>(wq, wk, wv, wqkv,
                                        4096 * HID / 4, 1024 * HID / 4, 1024 * HID / 4);
  rmsnorm_kernel<<<SEQ, 256, 0, stream>>>(hidden, prew, hb);

  // fused QKV projection (bf16 x bf16), 768 blocks = 3/CU
  gemm_bt<false><<<dim3(NTOT / 128, SEQ / 128), 256, 0, stream>>>(
      hb, wqkv, qkvp, nullptr, nullptr, SEQ, NTOT, HID);

  cvt_kernel<<<2048, 256, 0, stream>>>(wo, wob, HID * HID / 4);   // after QKV GEMM

  qkrope_kernel<<<SEQ * (NQH + NKVH) / 4, 256, 0, stream>>>(qkvp, qnw, knw, cosb, sinb, hb, kr);
  vtrans_kernel<<<dim3(32, 4, 8), 256, 0, stream>>>(qkvp, vt);

  attn_kernel<<<dim3(16, 32), 256, 0, stream>>>(hb, kr, vt, qkvp);

  // O-proj: direct fp32 write + residual, 512 blocks (best of 5 tested variants)
  gemm_bt<true><<<dim3(HID / 128, SEQ / 128), 256, 0, stream>>>(
      qkvp, wob, nullptr, outp, hidden, SEQ, HID, HID);
}